// Round 7
// baseline (1757.146 us; speedup 1.0000x reference)
//
#include <hip/hip_runtime.h>
#include <math.h>

#define STEPS 19
#define THREADS 256
#define L2E 1.44269504088896340736f   // log2(e)

// Match clang's builtin signatures: fdot2 / cvt_pkrtz use __fp16 ext-vectors.
typedef __fp16 half2_t __attribute__((ext_vector_type(2)));

// d_ws layout (dword offsets)
#define O_WH1 0      // [50]  half2 {Wh1[0][k], Wh1[1][k]}
#define O_WZ1 50     // [50]  half2, pre-scaled by -log2(e)
#define O_WH2 100    // [25][20] half2 {Wh2[2k2][i], Wh2[2k2+1][i]}
#define O_WZ2 600    // [25][20] half2, pre-scaled
#define O_WH3 1100   // [2][10] half2 {Wh3[2i2][j], Wh3[2i2+1][j]}
#define O_WZ3 1120   // [2][10] half2, pre-scaled
#define O_BZ1 1140   // [50] float, -L2E*bz1
#define O_BZ2 1190   // [20] float, -L2E*bz2
#define O_BZ3 1210   // [2]  float, -L2E*bz3

__device__ __forceinline__ float lrelu(float x) {
    return fmaxf(x, 0.01f * x);
}

__device__ __forceinline__ float fast_exp2(float y) {
#if __has_builtin(__builtin_amdgcn_exp2f)
    return __builtin_amdgcn_exp2f(y);
#else
    return exp2f(y);
#endif
}

// sigmoid(x) where y = -log2(e)*x was accumulated directly (pre-scaled weights)
__device__ __forceinline__ float sigm2(float y) {
    return __builtin_amdgcn_rcpf(1.0f + fast_exp2(y));
}

__device__ __forceinline__ float fdot2(half2_t a, half2_t b, float c) {
#if __has_builtin(__builtin_amdgcn_fdot2)
    return __builtin_amdgcn_fdot2(a, b, c, false);   // v_dot2_f32_f16, full-rate
#else
    return fmaf((float)a.y, (float)b.y, fmaf((float)a.x, (float)b.x, c));
#endif
}

__device__ __forceinline__ half2_t pkrtz(float a, float b) {
#if __has_builtin(__builtin_amdgcn_cvt_pkrtz)
    return __builtin_amdgcn_cvt_pkrtz(a, b);         // v_cvt_pkrtz_f16_f32, 1 op
#else
    half2_t r; r.x = (__fp16)a; r.y = (__fp16)b; return r;
#endif
}

__device__ __forceinline__ half2_t uph(unsigned int u) {
    return __builtin_bit_cast(half2_t, u);
}

__device__ __forceinline__ unsigned int packh2(float a, float b) {
    half2_t h; h.x = (__fp16)a; h.y = (__fp16)b;     // RNE conversion for weights
    return __builtin_bit_cast(unsigned int, h);
}

// --- pack kernel: pair weights along contraction dim as half2; pre-scale z path ---
__global__ __launch_bounds__(256) void pack_kernel(
    const float* __restrict__ Wh1, const float* __restrict__ Wz1,
    const float* __restrict__ Wh2, const float* __restrict__ Wz2,
    const float* __restrict__ Wh3, const float* __restrict__ Wz3,
    const float* __restrict__ bz1, const float* __restrict__ bz2,
    const float* __restrict__ bz3,
    unsigned int* __restrict__ pw, float* __restrict__ pf)
{
    const int t = threadIdx.x;
    if (t < 50) {
        pw[O_WH1 + t] = packh2(Wh1[t], Wh1[50 + t]);
        pw[O_WZ1 + t] = packh2(-L2E * Wz1[t], -L2E * Wz1[50 + t]);
        pf[O_BZ1 + t] = -L2E * bz1[t];
    }
    for (int idx = t; idx < 500; idx += 256) {
        const int k2 = idx / 20, i = idx % 20;
        pw[O_WH2 + idx] = packh2(Wh2[(2 * k2) * 20 + i], Wh2[(2 * k2 + 1) * 20 + i]);
        pw[O_WZ2 + idx] = packh2(-L2E * Wz2[(2 * k2) * 20 + i],
                                 -L2E * Wz2[(2 * k2 + 1) * 20 + i]);
    }
    if (t < 20) {
        const int j = t / 10, i2 = t % 10;
        pw[O_WH3 + t] = packh2(Wh3[(2 * i2) * 2 + j], Wh3[(2 * i2 + 1) * 2 + j]);
        pw[O_WZ3 + t] = packh2(-L2E * Wz3[(2 * i2) * 2 + j],
                               -L2E * Wz3[(2 * i2 + 1) * 2 + j]);
        pf[O_BZ2 + t] = -L2E * bz2[t];
    }
    if (t < 2) pf[O_BZ3 + t] = -L2E * bz3[t];
}

// --- main kernel: weights via scalar cache (uniform loads), MACs via v_dot2_f32_f16 ---
__global__ __launch_bounds__(THREADS) void recurrent_kernel(
    const float* __restrict__ w,
    const float* __restrict__ bh1, const float* __restrict__ bh2,
    const float* __restrict__ bh3,
    const unsigned int* __restrict__ pw, const float* __restrict__ pf,
    float* __restrict__ out, int nrows)
{
    const int row = blockIdx.x * THREADS + threadIdx.x;
    if (row >= nrows) return;

    const float2 w2 = *(const float2*)(w + 2 * (size_t)row);
    float h0 = w2.x, h1 = w2.y;

    float* __restrict__ orow = out + (size_t)row * (STEPS * 2);

    #pragma unroll 1          // keep step body ~14KB: I$-friendly
    for (int s = 0; s < STEPS; ++s) {
        half2_t h01 = pkrtz(h0, h1);
        float acc[20];

        // ---- h path: [2]->[50]->[20] fused, dot2 over k-pairs ----
        #pragma unroll
        for (int i = 0; i < 20; ++i) acc[i] = bh2[i];
        #pragma unroll
        for (int k2 = 0; k2 < 25; ++k2) {
            const float a0 = lrelu(fdot2(h01, uph(pw[O_WH1 + 2 * k2]),     bh1[2 * k2]));
            const float a1 = lrelu(fdot2(h01, uph(pw[O_WH1 + 2 * k2 + 1]), bh1[2 * k2 + 1]));
            const half2_t ap = pkrtz(a0, a1);
            #pragma unroll
            for (int i = 0; i < 20; ++i)
                acc[i] = fdot2(ap, uph(pw[O_WH2 + k2 * 20 + i]), acc[i]);
        }
        // h layer3: [20]->[2], dot2 over i-pairs
        float nh0 = bh3[0], nh1 = bh3[1];
        #pragma unroll
        for (int i2 = 0; i2 < 10; ++i2) {
            const half2_t lp = pkrtz(lrelu(acc[2 * i2]), lrelu(acc[2 * i2 + 1]));
            nh0 = fdot2(lp, uph(pw[O_WH3 + i2]),      nh0);
            nh1 = fdot2(lp, uph(pw[O_WH3 + 10 + i2]), nh1);
        }
        h0 = lrelu(nh0); h1 = lrelu(nh1);
        const half2_t g01 = pkrtz(h0, h1);

        // ---- z path (new h); all z weights/biases pre-scaled by -log2(e) ----
        #pragma unroll
        for (int i = 0; i < 20; ++i) acc[i] = pf[O_BZ2 + i];
        #pragma unroll
        for (int k2 = 0; k2 < 25; ++k2) {
            const float y0 = fdot2(g01, uph(pw[O_WZ1 + 2 * k2]),     pf[O_BZ1 + 2 * k2]);
            const float y1 = fdot2(g01, uph(pw[O_WZ1 + 2 * k2 + 1]), pf[O_BZ1 + 2 * k2 + 1]);
            const half2_t zp = pkrtz(sigm2(y0), sigm2(y1));
            #pragma unroll
            for (int i = 0; i < 20; ++i)
                acc[i] = fdot2(zp, uph(pw[O_WZ2 + k2 * 20 + i]), acc[i]);
        }
        float zo0 = pf[O_BZ3], zo1 = pf[O_BZ3 + 1];
        #pragma unroll
        for (int i2 = 0; i2 < 10; ++i2) {
            const half2_t sp = pkrtz(sigm2(acc[2 * i2]), sigm2(acc[2 * i2 + 1]));
            zo0 = fdot2(sp, uph(pw[O_WZ3 + i2]),      zo0);
            zo1 = fdot2(sp, uph(pw[O_WZ3 + 10 + i2]), zo1);
        }

        float2 o; o.x = sigm2(zo0); o.y = sigm2(zo1);
        *(float2*)(orow + 2 * s) = o;
    }
}

extern "C" void kernel_launch(void* const* d_in, const int* in_sizes, int n_in,
                              void* d_out, int out_size, void* d_ws, size_t ws_size,
                              hipStream_t stream) {
    const float* w   = (const float*)d_in[0];
    const float* Wh1 = (const float*)d_in[1];
    const float* bh1 = (const float*)d_in[2];
    const float* Wh2 = (const float*)d_in[3];
    const float* bh2 = (const float*)d_in[4];
    const float* Wh3 = (const float*)d_in[5];
    const float* bh3 = (const float*)d_in[6];
    const float* Wz1 = (const float*)d_in[7];
    const float* bz1 = (const float*)d_in[8];
    const float* Wz2 = (const float*)d_in[9];
    const float* bz2 = (const float*)d_in[10];
    const float* Wz3 = (const float*)d_in[11];
    const float* bz3 = (const float*)d_in[12];
    float* out = (float*)d_out;

    unsigned int* pw = (unsigned int*)d_ws;
    float*        pf = (float*)d_ws;

    pack_kernel<<<1, 256, 0, stream>>>(Wh1, Wz1, Wh2, Wz2, Wh3, Wz3,
                                       bz1, bz2, bz3, pw, pf);

    const int nrows = in_sizes[0] / 2;  // w is [B,2]
    const int blocks = (nrows + THREADS - 1) / THREADS;
    recurrent_kernel<<<blocks, THREADS, 0, stream>>>(
        w, bh1, bh2, bh3, (const unsigned int*)d_ws, (const float*)d_ws, out, nrows);
}

// Round 8
// 857.516 us; speedup vs baseline: 2.0491x; 2.0491x over previous
//
#include <hip/hip_runtime.h>
#include <math.h>

#define STEPS 19
#define THREADS 256
#define L2E 1.44269504088896340736f   // log2(e)

typedef _Float16 half8  __attribute__((ext_vector_type(8)));   // MFMA A/B frag (4 VGPR)
typedef float    floatx4 __attribute__((ext_vector_type(4)));  // MFMA C/D frag
typedef __fp16   half2_t __attribute__((ext_vector_type(2)));  // cvt_pkrtz type

#define ROW_BYTES 144              // 72 halves/row: 16B-aligned, conflict-free staging
#define WAVE_LDS  (64 * ROW_BYTES) // 9216 B per wave (C-stage overlays the front)
#define CSTRIDE   22               // dwords per C-stage row (conflict-free writes)

// d_ws byte offsets
#define WS_BH   0                  // h-layer2 B-frags  [u][kk][lane] * 16B = 4096
#define WS_BZ   4096               // z-layer2 B-frags (pre-scaled by -log2e) = 4096
#define WS_WZ1  8192               // 100 f32: -L2E*Wz1
#define WS_BZ1  8592               // 50  f32: -L2E*bz1
#define WS_WZ3  8792               // 40  f32: -L2E*Wz3
#define WS_BZ3  8952               // 2   f32: -L2E*bz3

#define LDS_FENCE() asm volatile("" ::: "memory")  // block compiler cross-phase reordering

__device__ __forceinline__ float lrelu(float x) { return fmaxf(x, 0.01f * x); }
__device__ __forceinline__ float sigm2(float y) {   // sigmoid with -log2e pre-folded
    return __builtin_amdgcn_rcpf(1.0f + __builtin_amdgcn_exp2f(y));
}
__device__ __forceinline__ unsigned int pkrtz_u(float a, float b) {
    return __builtin_bit_cast(unsigned int, __builtin_amdgcn_cvt_pkrtz(a, b));
}
__device__ __forceinline__ unsigned int packh2(float a, float b) {
    half2_t h; h.x = (__fp16)a; h.y = (__fp16)b;
    return __builtin_bit_cast(unsigned int, h);
}

// --- pack kernel: B-fragments for the two 50->20 MFMA layers + scaled z params ---
// B layout (16x16x32 f16): lane holds B[k=(lane>>4)*8+j][n=lane&15], j=0..7.
// Bias folded at k==50 (A supplies 1.0 there); k>50 rows are ZERO (annihilates A pad).
__global__ __launch_bounds__(256) void pack_kernel(
    const float* __restrict__ Wh2, const float* __restrict__ bh2,
    const float* __restrict__ Wz1, const float* __restrict__ bz1,
    const float* __restrict__ Wz2, const float* __restrict__ bz2,
    const float* __restrict__ Wz3, const float* __restrict__ bz3,
    char* __restrict__ ws)
{
    const int t = threadIdx.x;
    for (int e = t; e < 512; e += 256) {
        const int layer = e >> 8, r = e & 255;
        const int u = r >> 7, kk = (r >> 6) & 1, lane = r & 63;
        const int n = u * 16 + (lane & 15);
        const float* W2 = layer ? Wz2 : Wh2;
        const float* b2 = layer ? bz2 : bh2;
        const float scale = layer ? -L2E : 1.0f;
        unsigned int dw[4];
        #pragma unroll
        for (int d = 0; d < 4; ++d) {
            float v[2];
            #pragma unroll
            for (int h = 0; h < 2; ++h) {
                const int k = kk * 32 + ((lane >> 4) & 3) * 8 + 2 * d + h;
                float x = 0.0f;
                if (n < 20) {
                    if (k < 50)       x = W2[k * 20 + n] * scale;
                    else if (k == 50) x = b2[n] * scale;
                }
                v[h] = x;
            }
            dw[d] = packh2(v[0], v[1]);
        }
        *(uint4*)(ws + (layer ? WS_BZ : WS_BH) + (size_t)((u * 2 + kk) * 64 + lane) * 16)
            = make_uint4(dw[0], dw[1], dw[2], dw[3]);
    }
    if (t < 100) ((float*)(ws + WS_WZ1))[t] = -L2E * Wz1[t];
    if (t < 50)  ((float*)(ws + WS_BZ1))[t] = -L2E * bz1[t];
    if (t < 40)  ((float*)(ws + WS_WZ3))[t] = -L2E * Wz3[t];
    if (t < 2)   ((float*)(ws + WS_BZ3))[t] = -L2E * bz3[t];
}

__global__ __launch_bounds__(THREADS)
__attribute__((amdgpu_waves_per_eu(1, 2)))   // budget 256 VGPR: no spill (need ~140)
void recurrent_kernel(
    const float* __restrict__ w,
    const float* __restrict__ Wh1, const float* __restrict__ bh1,
    const float* __restrict__ Wh3, const float* __restrict__ bh3,
    const char* __restrict__ ws,
    float* __restrict__ out, int nrows)
{
    __shared__ __align__(16) char lds[4 * WAVE_LDS];
    const int t    = threadIdx.x;
    const int lane = t & 63;
    const int wid  = t >> 6;
    const int lq   = (lane >> 4) & 3;   // quad id (K-slice / row-group)
    const int ll   = lane & 15;
    char* base  = lds + wid * WAVE_LDS;
    char* myrow = base + lane * ROW_BYTES;

    // B fragments: loaded once, reused for all 19 steps.
    uint4 Bh[2][2], Bz[2][2];
    #pragma unroll
    for (int u = 0; u < 2; ++u)
        #pragma unroll
        for (int kk = 0; kk < 2; ++kk) {
            Bh[u][kk] = *(const uint4*)(ws + WS_BH + (size_t)((u * 2 + kk) * 64 + lane) * 16);
            Bz[u][kk] = *(const uint4*)(ws + WS_BZ + (size_t)((u * 2 + kk) * 64 + lane) * 16);
        }
    const float* Wz1s = (const float*)(ws + WS_WZ1);
    const float* bz1s = (const float*)(ws + WS_BZ1);
    const float* Wz3s = (const float*)(ws + WS_WZ3);
    const float* bz3s = (const float*)(ws + WS_BZ3);

    const int row = blockIdx.x * THREADS + t;
    const bool ok = row < nrows;
    const int rr  = ok ? row : 0;
    const float2 w2 = *(const float2*)(w + 2 * (size_t)rr);
    float h0 = w2.x, h1 = w2.y;
    float* orow = out + (size_t)row * (STEPS * 2);

    #pragma unroll 1
    for (int s = 0; s < STEPS; ++s) {
        // ======== h path ========
        // L1h per-lane (fp32, scalar-cache weights); stage row as f16 (k=50 -> 1.0 bias slot).
        #pragma unroll
        for (int b = 0; b < 6; ++b) {
            float av[8];
            #pragma unroll
            for (int j = 0; j < 8; ++j) {
                const int k = b * 8 + j;
                av[j] = lrelu(fmaf(h1, Wh1[50 + k], fmaf(h0, Wh1[k], bh1[k])));
            }
            *(uint4*)(myrow + b * 16) = make_uint4(
                pkrtz_u(av[0], av[1]), pkrtz_u(av[2], av[3]),
                pkrtz_u(av[4], av[5]), pkrtz_u(av[6], av[7]));
        }
        {
            const float a48 = lrelu(fmaf(h1, Wh1[98], fmaf(h0, Wh1[48], bh1[48])));
            const float a49 = lrelu(fmaf(h1, Wh1[99], fmaf(h0, Wh1[49], bh1[49])));
            *(uint4*)(myrow + 96)  = make_uint4(pkrtz_u(a48, a49), pkrtz_u(1.0f, 0.0f), 0u, 0u);
            *(uint4*)(myrow + 112) = make_uint4(0u, 0u, 0u, 0u);
        }
        LDS_FENCE();
        // MFMA: [64x64] x [64x32] (20 valid N) ; A[m=ll][k=lq*8+j]
        floatx4 C[4][2];
        #pragma unroll
        for (int mt = 0; mt < 4; ++mt) { C[mt][0] = (floatx4)0.0f; C[mt][1] = (floatx4)0.0f; }
        #pragma unroll
        for (int mt = 0; mt < 4; ++mt) {
            const char* ab = base + (mt * 16 + ll) * ROW_BYTES + lq * 16;
            const half8 A0 = __builtin_bit_cast(half8, *(const uint4*)(ab));
            const half8 A1 = __builtin_bit_cast(half8, *(const uint4*)(ab + 64));
            C[mt][0] = __builtin_amdgcn_mfma_f32_16x16x32_f16(A0, __builtin_bit_cast(half8, Bh[0][0]), C[mt][0], 0, 0, 0);
            C[mt][1] = __builtin_amdgcn_mfma_f32_16x16x32_f16(A0, __builtin_bit_cast(half8, Bh[1][0]), C[mt][1], 0, 0, 0);
            C[mt][0] = __builtin_amdgcn_mfma_f32_16x16x32_f16(A1, __builtin_bit_cast(half8, Bh[0][1]), C[mt][0], 0, 0, 0);
            C[mt][1] = __builtin_amdgcn_mfma_f32_16x16x32_f16(A1, __builtin_bit_cast(half8, Bh[1][1]), C[mt][1], 0, 0, 0);
        }
        LDS_FENCE();
        // C (col=ll, row=lq*4+i) -> per-lane rows via stride-22 stage
        #pragma unroll
        for (int mt = 0; mt < 4; ++mt)
            #pragma unroll
            for (int u = 0; u < 2; ++u)
                #pragma unroll
                for (int i = 0; i < 4; ++i)
                    *(float*)(base + (size_t)(((mt * 16 + lq * 4 + i) * CSTRIDE) + u * 16 + ll) * 4) = C[mt][u][i];
        LDS_FENCE();
        float a2[20];
        #pragma unroll
        for (int p = 0; p < 10; ++p) {
            const float2 v = *(const float2*)(base + (size_t)(lane * CSTRIDE + 2 * p) * 4);
            a2[2 * p] = v.x; a2[2 * p + 1] = v.y;
        }
        LDS_FENCE();
        float nh0 = bh3[0], nh1 = bh3[1];
        #pragma unroll
        for (int i = 0; i < 20; ++i) {
            const float a = lrelu(a2[i]);
            nh0 = fmaf(a, Wh3[2 * i], nh0);
            nh1 = fmaf(a, Wh3[2 * i + 1], nh1);
        }
        h0 = lrelu(nh0); h1 = lrelu(nh1);

        // ======== z path (uses NEW h; all z weights pre-scaled by -log2e) ========
        #pragma unroll
        for (int b = 0; b < 6; ++b) {
            float zv[8];
            #pragma unroll
            for (int j = 0; j < 8; ++j) {
                const int k = b * 8 + j;
                zv[j] = sigm2(fmaf(h1, Wz1s[50 + k], fmaf(h0, Wz1s[k], bz1s[k])));
            }
            *(uint4*)(myrow + b * 16) = make_uint4(
                pkrtz_u(zv[0], zv[1]), pkrtz_u(zv[2], zv[3]),
                pkrtz_u(zv[4], zv[5]), pkrtz_u(zv[6], zv[7]));
        }
        {
            const float z48 = sigm2(fmaf(h1, Wz1s[98], fmaf(h0, Wz1s[48], bz1s[48])));
            const float z49 = sigm2(fmaf(h1, Wz1s[99], fmaf(h0, Wz1s[49], bz1s[49])));
            *(uint4*)(myrow + 96)  = make_uint4(pkrtz_u(z48, z49), pkrtz_u(1.0f, 0.0f), 0u, 0u);
            *(uint4*)(myrow + 112) = make_uint4(0u, 0u, 0u, 0u);
        }
        LDS_FENCE();
        #pragma unroll
        for (int mt = 0; mt < 4; ++mt) { C[mt][0] = (floatx4)0.0f; C[mt][1] = (floatx4)0.0f; }
        #pragma unroll
        for (int mt = 0; mt < 4; ++mt) {
            const char* ab = base + (mt * 16 + ll) * ROW_BYTES + lq * 16;
            const half8 A0 = __builtin_bit_cast(half8, *(const uint4*)(ab));
            const half8 A1 = __builtin_bit_cast(half8, *(const uint4*)(ab + 64));
            C[mt][0] = __builtin_amdgcn_mfma_f32_16x16x32_f16(A0, __builtin_bit_cast(half8, Bz[0][0]), C[mt][0], 0, 0, 0);
            C[mt][1] = __builtin_amdgcn_mfma_f32_16x16x32_f16(A0, __builtin_bit_cast(half8, Bz[1][0]), C[mt][1], 0, 0, 0);
            C[mt][0] = __builtin_amdgcn_mfma_f32_16x16x32_f16(A1, __builtin_bit_cast(half8, Bz[0][1]), C[mt][0], 0, 0, 0);
            C[mt][1] = __builtin_amdgcn_mfma_f32_16x16x32_f16(A1, __builtin_bit_cast(half8, Bz[1][1]), C[mt][1], 0, 0, 0);
        }
        LDS_FENCE();
        #pragma unroll
        for (int mt = 0; mt < 4; ++mt)
            #pragma unroll
            for (int u = 0; u < 2; ++u)
                #pragma unroll
                for (int i = 0; i < 4; ++i)
                    *(float*)(base + (size_t)(((mt * 16 + lq * 4 + i) * CSTRIDE) + u * 16 + ll) * 4) = C[mt][u][i];
        LDS_FENCE();
        #pragma unroll
        for (int p = 0; p < 10; ++p) {
            const float2 v = *(const float2*)(base + (size_t)(lane * CSTRIDE + 2 * p) * 4);
            a2[2 * p] = v.x; a2[2 * p + 1] = v.y;
        }
        LDS_FENCE();
        float zo0 = bz3s[0], zo1 = bz3s[1];
        #pragma unroll
        for (int i = 0; i < 20; ++i) {
            const float zz = sigm2(a2[i]);
            zo0 = fmaf(zz, Wz3s[2 * i], zo0);
            zo1 = fmaf(zz, Wz3s[2 * i + 1], zo1);
        }
        if (ok) {
            float2 o; o.x = sigm2(zo0); o.y = sigm2(zo1);
            *(float2*)(orow + 2 * s) = o;
        }
    }
}

extern "C" void kernel_launch(void* const* d_in, const int* in_sizes, int n_in,
                              void* d_out, int out_size, void* d_ws, size_t ws_size,
                              hipStream_t stream) {
    const float* w   = (const float*)d_in[0];
    const float* Wh1 = (const float*)d_in[1];
    const float* bh1 = (const float*)d_in[2];
    const float* Wh2 = (const float*)d_in[3];
    const float* bh2 = (const float*)d_in[4];
    const float* Wh3 = (const float*)d_in[5];
    const float* bh3 = (const float*)d_in[6];
    const float* Wz1 = (const float*)d_in[7];
    const float* bz1 = (const float*)d_in[8];
    const float* Wz2 = (const float*)d_in[9];
    const float* bz2 = (const float*)d_in[10];
    const float* Wz3 = (const float*)d_in[11];
    const float* bz3 = (const float*)d_in[12];
    float* out = (float*)d_out;

    pack_kernel<<<1, 256, 0, stream>>>(Wh2, bh2, Wz1, bz1, Wz2, bz2, Wz3, bz3,
                                       (char*)d_ws);

    const int nrows = in_sizes[0] / 2;  // w is [B,2]
    const int blocks = (nrows + THREADS - 1) / THREADS;
    recurrent_kernel<<<blocks, THREADS, 0, stream>>>(
        w, Wh1, bh1, Wh3, bh3, (const char*)d_ws, out, nrows);
}

// Round 9
// 768.213 us; speedup vs baseline: 2.2873x; 1.1162x over previous
//
#include <hip/hip_runtime.h>
#include <math.h>

#define STEPS 19
#define THREADS 256
#define L2E 1.44269504088896340736f   // log2(e)

typedef _Float16 half8  __attribute__((ext_vector_type(8)));   // MFMA A/B frag (4 VGPR)
typedef float    floatx4 __attribute__((ext_vector_type(4)));  // MFMA C/D frag
typedef __fp16   half2_t __attribute__((ext_vector_type(2)));  // cvt_pkrtz type

#define ROW_BYTES 144              // 72 halves/row: 16B-aligned, conflict-free staging
#define WAVE_LDS  (64 * ROW_BYTES) // 9216 B per wave (C-stage overlays the front)
#define CSTRIDE   22               // dwords per C-stage row (2-way bank aliasing = free)

// d_ws byte offsets
#define WS_BH   0                  // h-layer2 B-frags  [u][kk][lane] * 16B = 4096
#define WS_BZ   4096               // z-layer2 B-frags (pre-scaled by -log2e) = 4096
#define WS_WZ1  8192               // 100 f32: -L2E*Wz1
#define WS_BZ1  8592               // 50  f32: -L2E*bz1
#define WS_WZ3  8792               // 40  f32: -L2E*Wz3
#define WS_BZ3  8952               // 2   f32: -L2E*bz3

#define LDS_FENCE() asm volatile("" ::: "memory")  // block compiler cross-phase reordering

__device__ __forceinline__ float lrelu(float x) { return fmaxf(x, 0.01f * x); }
__device__ __forceinline__ float sigm2(float y) {   // sigmoid with -log2e pre-folded
    return __builtin_amdgcn_rcpf(1.0f + __builtin_amdgcn_exp2f(y));
}
__device__ __forceinline__ unsigned int pkrtz_u(float a, float b) {
    return __builtin_bit_cast(unsigned int, __builtin_amdgcn_cvt_pkrtz(a, b));
}
__device__ __forceinline__ unsigned int packh2(float a, float b) {
    half2_t h; h.x = (__fp16)a; h.y = (__fp16)b;
    return __builtin_bit_cast(unsigned int, h);
}

// --- pack kernel: B-fragments for the two 50->20 MFMA layers + scaled z params ---
// B layout (16x16x32 f16): lane holds B[k=(lane>>4)*8+j][n=lane&15], j=0..7.
// Bias folded at k==50 (A supplies 1.0 there); k>50 rows are ZERO (annihilates A pad).
__global__ __launch_bounds__(256) void pack_kernel(
    const float* __restrict__ Wh2, const float* __restrict__ bh2,
    const float* __restrict__ Wz1, const float* __restrict__ bz1,
    const float* __restrict__ Wz2, const float* __restrict__ bz2,
    const float* __restrict__ Wz3, const float* __restrict__ bz3,
    char* __restrict__ ws)
{
    const int t = threadIdx.x;
    for (int e = t; e < 512; e += 256) {
        const int layer = e >> 8, r = e & 255;
        const int u = r >> 7, kk = (r >> 6) & 1, lane = r & 63;
        const int n = u * 16 + (lane & 15);
        const float* W2 = layer ? Wz2 : Wh2;
        const float* b2 = layer ? bz2 : bh2;
        const float scale = layer ? -L2E : 1.0f;
        unsigned int dw[4];
        #pragma unroll
        for (int d = 0; d < 4; ++d) {
            float v[2];
            #pragma unroll
            for (int h = 0; h < 2; ++h) {
                const int k = kk * 32 + ((lane >> 4) & 3) * 8 + 2 * d + h;
                float x = 0.0f;
                if (n < 20) {
                    if (k < 50)       x = W2[k * 20 + n] * scale;
                    else if (k == 50) x = b2[n] * scale;
                }
                v[h] = x;
            }
            dw[d] = packh2(v[0], v[1]);
        }
        *(uint4*)(ws + (layer ? WS_BZ : WS_BH) + (size_t)((u * 2 + kk) * 64 + lane) * 16)
            = make_uint4(dw[0], dw[1], dw[2], dw[3]);
    }
    if (t < 100) ((float*)(ws + WS_WZ1))[t] = -L2E * Wz1[t];
    if (t < 50)  ((float*)(ws + WS_BZ1))[t] = -L2E * bz1[t];
    if (t < 40)  ((float*)(ws + WS_WZ3))[t] = -L2E * Wz3[t];
    if (t < 2)   ((float*)(ws + WS_BZ3))[t] = -L2E * bz3[t];
}

__global__ __launch_bounds__(THREADS)
__attribute__((amdgpu_waves_per_eu(2)))   // min 2 (RA <= 256 VGPR), NO max cap:
                                          // VGPR=108 & LDS=36864 both allow 4 waves/EU
void recurrent_kernel(
    const float* __restrict__ w,
    const float* __restrict__ Wh1, const float* __restrict__ bh1,
    const float* __restrict__ Wh3, const float* __restrict__ bh3,
    const char* __restrict__ ws,
    float* __restrict__ out, int nrows)
{
    __shared__ __align__(16) char lds[4 * WAVE_LDS];
    const int t    = threadIdx.x;
    const int lane = t & 63;
    const int wid  = t >> 6;
    const int lq   = (lane >> 4) & 3;   // quad id (K-slice / row-group)
    const int ll   = lane & 15;
    char* base  = lds + wid * WAVE_LDS;
    char* myrow = base + lane * ROW_BYTES;

    // B fragments: loaded once, reused for all 19 steps.
    uint4 Bh[2][2], Bz[2][2];
    #pragma unroll
    for (int u = 0; u < 2; ++u)
        #pragma unroll
        for (int kk = 0; kk < 2; ++kk) {
            Bh[u][kk] = *(const uint4*)(ws + WS_BH + (size_t)((u * 2 + kk) * 64 + lane) * 16);
            Bz[u][kk] = *(const uint4*)(ws + WS_BZ + (size_t)((u * 2 + kk) * 64 + lane) * 16);
        }
    const float* Wz1s = (const float*)(ws + WS_WZ1);
    const float* bz1s = (const float*)(ws + WS_BZ1);
    const float* Wz3s = (const float*)(ws + WS_WZ3);
    const float* bz3s = (const float*)(ws + WS_BZ3);

    const int row = blockIdx.x * THREADS + t;
    const bool ok = row < nrows;
    const int rr  = ok ? row : 0;
    const float2 w2 = *(const float2*)(w + 2 * (size_t)rr);
    float h0 = w2.x, h1 = w2.y;
    float* orow = out + (size_t)row * (STEPS * 2);

    #pragma unroll 1
    for (int s = 0; s < STEPS; ++s) {
        // ======== h path ========
        // L1h per-lane (fp32, scalar-cache weights); stage row as f16 (k=50 -> 1.0 bias slot).
        #pragma unroll
        for (int b = 0; b < 6; ++b) {
            float av[8];
            #pragma unroll
            for (int j = 0; j < 8; ++j) {
                const int k = b * 8 + j;
                av[j] = lrelu(fmaf(h1, Wh1[50 + k], fmaf(h0, Wh1[k], bh1[k])));
            }
            *(uint4*)(myrow + b * 16) = make_uint4(
                pkrtz_u(av[0], av[1]), pkrtz_u(av[2], av[3]),
                pkrtz_u(av[4], av[5]), pkrtz_u(av[6], av[7]));
        }
        {
            const float a48 = lrelu(fmaf(h1, Wh1[98], fmaf(h0, Wh1[48], bh1[48])));
            const float a49 = lrelu(fmaf(h1, Wh1[99], fmaf(h0, Wh1[49], bh1[49])));
            *(uint4*)(myrow + 96)  = make_uint4(pkrtz_u(a48, a49), pkrtz_u(1.0f, 0.0f), 0u, 0u);
            *(uint4*)(myrow + 112) = make_uint4(0u, 0u, 0u, 0u);
        }
        LDS_FENCE();
        // MFMA: [64x64] x [64x32] (20 valid N) ; A[m=ll][k=lq*8+j]
        floatx4 C[4][2];
        #pragma unroll
        for (int mt = 0; mt < 4; ++mt) { C[mt][0] = (floatx4)0.0f; C[mt][1] = (floatx4)0.0f; }
        #pragma unroll
        for (int mt = 0; mt < 4; ++mt) {
            const char* ab = base + (mt * 16 + ll) * ROW_BYTES + lq * 16;
            const half8 A0 = __builtin_bit_cast(half8, *(const uint4*)(ab));
            const half8 A1 = __builtin_bit_cast(half8, *(const uint4*)(ab + 64));
            C[mt][0] = __builtin_amdgcn_mfma_f32_16x16x32_f16(A0, __builtin_bit_cast(half8, Bh[0][0]), C[mt][0], 0, 0, 0);
            C[mt][1] = __builtin_amdgcn_mfma_f32_16x16x32_f16(A0, __builtin_bit_cast(half8, Bh[1][0]), C[mt][1], 0, 0, 0);
            C[mt][0] = __builtin_amdgcn_mfma_f32_16x16x32_f16(A1, __builtin_bit_cast(half8, Bh[0][1]), C[mt][0], 0, 0, 0);
            C[mt][1] = __builtin_amdgcn_mfma_f32_16x16x32_f16(A1, __builtin_bit_cast(half8, Bh[1][1]), C[mt][1], 0, 0, 0);
        }
        LDS_FENCE();
        // C (col=ll, row=lq*4+i) -> per-lane rows via stride-22 stage
        #pragma unroll
        for (int mt = 0; mt < 4; ++mt)
            #pragma unroll
            for (int u = 0; u < 2; ++u)
                #pragma unroll
                for (int i = 0; i < 4; ++i)
                    *(float*)(base + (size_t)(((mt * 16 + lq * 4 + i) * CSTRIDE) + u * 16 + ll) * 4) = C[mt][u][i];
        LDS_FENCE();
        float a2[20];
        #pragma unroll
        for (int p = 0; p < 10; ++p) {
            const float2 v = *(const float2*)(base + (size_t)(lane * CSTRIDE + 2 * p) * 4);
            a2[2 * p] = v.x; a2[2 * p + 1] = v.y;
        }
        LDS_FENCE();
        float nh0 = bh3[0], nh1 = bh3[1];
        #pragma unroll
        for (int i = 0; i < 20; ++i) {
            const float a = lrelu(a2[i]);
            nh0 = fmaf(a, Wh3[2 * i], nh0);
            nh1 = fmaf(a, Wh3[2 * i + 1], nh1);
        }
        h0 = lrelu(nh0); h1 = lrelu(nh1);

        // ======== z path (uses NEW h; all z weights pre-scaled by -log2e) ========
        #pragma unroll
        for (int b = 0; b < 6; ++b) {
            float zv[8];
            #pragma unroll
            for (int j = 0; j < 8; ++j) {
                const int k = b * 8 + j;
                zv[j] = sigm2(fmaf(h1, Wz1s[50 + k], fmaf(h0, Wz1s[k], bz1s[k])));
            }
            *(uint4*)(myrow + b * 16) = make_uint4(
                pkrtz_u(zv[0], zv[1]), pkrtz_u(zv[2], zv[3]),
                pkrtz_u(zv[4], zv[5]), pkrtz_u(zv[6], zv[7]));
        }
        {
            const float z48 = sigm2(fmaf(h1, Wz1s[98], fmaf(h0, Wz1s[48], bz1s[48])));
            const float z49 = sigm2(fmaf(h1, Wz1s[99], fmaf(h0, Wz1s[49], bz1s[49])));
            *(uint4*)(myrow + 96)  = make_uint4(pkrtz_u(z48, z49), pkrtz_u(1.0f, 0.0f), 0u, 0u);
            *(uint4*)(myrow + 112) = make_uint4(0u, 0u, 0u, 0u);
        }
        LDS_FENCE();
        #pragma unroll
        for (int mt = 0; mt < 4; ++mt) { C[mt][0] = (floatx4)0.0f; C[mt][1] = (floatx4)0.0f; }
        #pragma unroll
        for (int mt = 0; mt < 4; ++mt) {
            const char* ab = base + (mt * 16 + ll) * ROW_BYTES + lq * 16;
            const half8 A0 = __builtin_bit_cast(half8, *(const uint4*)(ab));
            const half8 A1 = __builtin_bit_cast(half8, *(const uint4*)(ab + 64));
            C[mt][0] = __builtin_amdgcn_mfma_f32_16x16x32_f16(A0, __builtin_bit_cast(half8, Bz[0][0]), C[mt][0], 0, 0, 0);
            C[mt][1] = __builtin_amdgcn_mfma_f32_16x16x32_f16(A0, __builtin_bit_cast(half8, Bz[1][0]), C[mt][1], 0, 0, 0);
            C[mt][0] = __builtin_amdgcn_mfma_f32_16x16x32_f16(A1, __builtin_bit_cast(half8, Bz[0][1]), C[mt][0], 0, 0, 0);
            C[mt][1] = __builtin_amdgcn_mfma_f32_16x16x32_f16(A1, __builtin_bit_cast(half8, Bz[1][1]), C[mt][1], 0, 0, 0);
        }
        LDS_FENCE();
        #pragma unroll
        for (int mt = 0; mt < 4; ++mt)
            #pragma unroll
            for (int u = 0; u < 2; ++u)
                #pragma unroll
                for (int i = 0; i < 4; ++i)
                    *(float*)(base + (size_t)(((mt * 16 + lq * 4 + i) * CSTRIDE) + u * 16 + ll) * 4) = C[mt][u][i];
        LDS_FENCE();
        #pragma unroll
        for (int p = 0; p < 10; ++p) {
            const float2 v = *(const float2*)(base + (size_t)(lane * CSTRIDE + 2 * p) * 4);
            a2[2 * p] = v.x; a2[2 * p + 1] = v.y;
        }
        LDS_FENCE();
        float zo0 = bz3s[0], zo1 = bz3s[1];
        #pragma unroll
        for (int i = 0; i < 20; ++i) {
            const float zz = sigm2(a2[i]);
            zo0 = fmaf(zz, Wz3s[2 * i], zo0);
            zo1 = fmaf(zz, Wz3s[2 * i + 1], zo1);
        }
        if (ok) {
            float2 o; o.x = sigm2(zo0); o.y = sigm2(zo1);
            *(float2*)(orow + 2 * s) = o;
        }
    }
}

extern "C" void kernel_launch(void* const* d_in, const int* in_sizes, int n_in,
                              void* d_out, int out_size, void* d_ws, size_t ws_size,
                              hipStream_t stream) {
    const float* w   = (const float*)d_in[0];
    const float* Wh1 = (const float*)d_in[1];
    const float* bh1 = (const float*)d_in[2];
    const float* Wh2 = (const float*)d_in[3];
    const float* bh2 = (const float*)d_in[4];
    const float* Wh3 = (const float*)d_in[5];
    const float* bh3 = (const float*)d_in[6];
    const float* Wz1 = (const float*)d_in[7];
    const float* bz1 = (const float*)d_in[8];
    const float* Wz2 = (const float*)d_in[9];
    const float* bz2 = (const float*)d_in[10];
    const float* Wz3 = (const float*)d_in[11];
    const float* bz3 = (const float*)d_in[12];
    float* out = (float*)d_out;

    pack_kernel<<<1, 256, 0, stream>>>(Wh2, bh2, Wz1, bz1, Wz2, bz2, Wz3, bz3,
                                       (char*)d_ws);

    const int nrows = in_sizes[0] / 2;  // w is [B,2]
    const int blocks = (nrows + THREADS - 1) / THREADS;
    recurrent_kernel<<<blocks, THREADS, 0, stream>>>(
        w, Wh1, bh1, Wh3, bh3, (const char*)d_ws, out, nrows);
}

// Round 11
// 671.021 us; speedup vs baseline: 2.6186x; 1.1448x over previous
//
#include <hip/hip_runtime.h>
#include <math.h>

#define STEPS 19
#define THREADS 256
#define L2E 1.44269504088896340736f   // log2(e)

typedef _Float16 half8   __attribute__((ext_vector_type(8)));   // MFMA A/B frag
typedef float    floatx4 __attribute__((ext_vector_type(4)));   // MFMA C/D frag
typedef __fp16   half2_t __attribute__((ext_vector_type(2)));   // packed f16 pair

#define WAVE_LDS 8192   // A-frags [kb][mt][fraglane]*16B = 2*4*64*16; C-stage (5120B) overlays

// d_ws byte offsets
#define WS_BH    0      // h-layer2 B-frags  [u][kk][lane]*16B = 4096
#define WS_BZ    4096   // z-layer2 B-frags (pre-scaled by -log2e) = 4096
#define WS_H1W0  8192   // 25 half2: {Wh1[0][2q],Wh1[0][2q+1]}
#define WS_H1W1  8292   // 25 half2: row 1
#define WS_H1B   8392   // 25 half2: bh1 pairs
#define WS_WZ1   8492   // 100 f32: -L2E*Wz1
#define WS_BZ1   8892   // 50  f32: -L2E*bz1
#define WS_WZ3   9092   // 40  f32: -L2E*Wz3
#define WS_BZ3   9252   // 2   f32: -L2E*bz3

#define LDS_FENCE() asm volatile("" ::: "memory")

__device__ __forceinline__ float lrelu(float x) { return fmaxf(x, 0.01f * x); }
__device__ __forceinline__ float sigm2(float y) {   // sigmoid, -log2e pre-folded
    return __builtin_amdgcn_rcpf(1.0f + __builtin_amdgcn_exp2f(y));
}
__device__ __forceinline__ unsigned int pkrtz_u(float a, float b) {
    return __builtin_bit_cast(unsigned int, __builtin_amdgcn_cvt_pkrtz(a, b));
}
__device__ __forceinline__ unsigned int packh2(float a, float b) {
    half2_t h; h.x = (__fp16)a; h.y = (__fp16)b;
    return __builtin_bit_cast(unsigned int, h);
}
__device__ __forceinline__ unsigned int h2bits(half2_t h) {
    return __builtin_bit_cast(unsigned int, h);
}
__device__ __forceinline__ half2_t bits2h(unsigned int u) {
    return __builtin_bit_cast(half2_t, u);
}

// --- pack kernel ---
__global__ __launch_bounds__(256) void pack_kernel(
    const float* __restrict__ Wh1, const float* __restrict__ bh1,
    const float* __restrict__ Wh2, const float* __restrict__ bh2,
    const float* __restrict__ Wz1, const float* __restrict__ bz1,
    const float* __restrict__ Wz2, const float* __restrict__ bz2,
    const float* __restrict__ Wz3, const float* __restrict__ bz3,
    char* __restrict__ ws)
{
    const int t = threadIdx.x;
    // B-frags (16x16x32 f16): lane holds B[k=(lane>>4)*8+j][n=lane&15], j=0..7.
    // Bias row at k==50 (A supplies 1.0); k>50 rows ZERO (annihilate A pad).
    for (int e = t; e < 512; e += 256) {
        const int layer = e >> 8, r = e & 255;
        const int u = r >> 7, kk = (r >> 6) & 1, lane = r & 63;
        const int n = u * 16 + (lane & 15);
        const float* W2 = layer ? Wz2 : Wh2;
        const float* b2 = layer ? bz2 : bh2;
        const float scale = layer ? -L2E : 1.0f;
        unsigned int dw[4];
        #pragma unroll
        for (int d = 0; d < 4; ++d) {
            float v[2];
            #pragma unroll
            for (int h = 0; h < 2; ++h) {
                const int k = kk * 32 + ((lane >> 4) & 3) * 8 + 2 * d + h;
                float x = 0.0f;
                if (n < 20) {
                    if (k < 50)       x = W2[k * 20 + n] * scale;
                    else if (k == 50) x = b2[n] * scale;
                }
                v[h] = x;
            }
            dw[d] = packh2(v[0], v[1]);
        }
        *(uint4*)(ws + (layer ? WS_BZ : WS_BH) + (size_t)((u * 2 + kk) * 64 + lane) * 16)
            = make_uint4(dw[0], dw[1], dw[2], dw[3]);
    }
    if (t < 25) {
        ((unsigned int*)(ws + WS_H1W0))[t] = packh2(Wh1[2 * t],      Wh1[2 * t + 1]);
        ((unsigned int*)(ws + WS_H1W1))[t] = packh2(Wh1[50 + 2 * t], Wh1[51 + 2 * t]);
        ((unsigned int*)(ws + WS_H1B))[t]  = packh2(bh1[2 * t],      bh1[2 * t + 1]);
    }
    if (t < 100) ((float*)(ws + WS_WZ1))[t] = -L2E * Wz1[t];
    if (t < 50)  ((float*)(ws + WS_BZ1))[t] = -L2E * bz1[t];
    if (t < 40)  ((float*)(ws + WS_WZ3))[t] = -L2E * Wz3[t];
    if (t < 2)   ((float*)(ws + WS_BZ3))[t] = -L2E * bz3[t];
}

__global__ __launch_bounds__(THREADS)
__attribute__((amdgpu_waves_per_eu(2)))   // min 2 => RA <= 256 VGPR; no max cap
void recurrent_kernel(
    const float* __restrict__ w,
    const float* __restrict__ Wh3, const float* __restrict__ bh3,
    const char* __restrict__ ws,
    float* __restrict__ out, int nrows)
{
    __shared__ __align__(16) char lds[4 * WAVE_LDS];
    const int t    = threadIdx.x;
    const int lane = t & 63;
    const int wid  = t >> 6;
    const int lq   = (lane >> 4) & 3;
    const int ll   = lane & 15;
    char* ldsw = lds + wid * WAVE_LDS;

    // A-frag staging bases. Write: lane m=lane owns tile mt=lane>>4, row ll=lane&15;
    // chunk c (k=8c..8c+7) -> ((c>>2)*4 + mt)*1024 + (c&3)*256 + ll*16.
    char* awb = ldsw + (lane >> 4) * 1024 + (lane & 15) * 16;
    // Read: frag-lane reads its own 16B slot; tile/half via immediates.
    const char* arb = ldsw + lane * 16;
    // C-stage (overlays A region): row stride 20 dwords. row = mt*16+lq*4+i, col = n.
    // u=0 col=ll; u=1 col=16+ll (ll<4 valid), invalid lanes wrap to col ll-4 and are
    // overwritten by the later u=0 writes (fence-ordered; DS in-order per wave).
    const int cmod = (ll < 4) ? (16 + ll) : (ll - 4);
    char* cw0 = ldsw + lq * 320 + ll * 4;
    char* cw1 = ldsw + lq * 320 + cmod * 4;
    const char* crb = ldsw + lane * 80;

    // B fragments: loaded once, reused all 19 steps.
    uint4 Bh[2][2], Bz[2][2];
    #pragma unroll
    for (int u = 0; u < 2; ++u)
        #pragma unroll
        for (int kk = 0; kk < 2; ++kk) {
            Bh[u][kk] = *(const uint4*)(ws + WS_BH + (size_t)((u * 2 + kk) * 64 + lane) * 16);
            Bz[u][kk] = *(const uint4*)(ws + WS_BZ + (size_t)((u * 2 + kk) * 64 + lane) * 16);
        }
    const unsigned int* W0p = (const unsigned int*)(ws + WS_H1W0);
    const unsigned int* W1p = (const unsigned int*)(ws + WS_H1W1);
    const unsigned int* B1p = (const unsigned int*)(ws + WS_H1B);
    const float* Wz1s = (const float*)(ws + WS_WZ1);
    const float* bz1s = (const float*)(ws + WS_BZ1);
    const float* Wz3s = (const float*)(ws + WS_WZ3);
    const float* bz3s = (const float*)(ws + WS_BZ3);

    const half2_t c001h = {(__fp16)0.01f, (__fp16)0.01f};
    const floatx4 ZC = {0.0f, 0.0f, 0.0f, 0.0f};   // persistent zero C-operand

    const int row = blockIdx.x * THREADS + t;
    const bool ok = row < nrows;
    const float2 w2 = *(const float2*)(w + 2 * (size_t)(ok ? row : 0));
    float h0 = w2.x, h1 = w2.y;
    float* orow = out + (size_t)row * (STEPS * 2);

    #pragma unroll 1
    for (int s = 0; s < STEPS; ++s) {
        // ======== h path: L1 in packed f16 (v_pk_fma/v_pk_max), direct frag staging ====
        {
            const __fp16 h0h = (__fp16)h0, h1h = (__fp16)h1;
            const half2_t h00 = {h0h, h0h};
            const half2_t h11 = {h1h, h1h};
            #pragma unroll
            for (int c = 0; c < 6; ++c) {
                unsigned int dw[4];
                #pragma unroll
                for (int p = 0; p < 4; ++p) {
                    const int q = c * 4 + p;         // pair q -> k=2q,2q+1
                    half2_t v = h11 * bits2h(W1p[q]) + (h00 * bits2h(W0p[q]) + bits2h(B1p[q]));
                    v = __builtin_elementwise_max(v, v * c001h);   // packed lrelu
                    dw[p] = h2bits(v);
                }
                *(uint4*)(awb + (c >> 2) * 4096 + (c & 3) * 256)
                    = make_uint4(dw[0], dw[1], dw[2], dw[3]);
            }
            {   // chunk 6: pair24 + bias slot (k=50 -> 1.0) + zeros
                half2_t v = h11 * bits2h(W1p[24]) + (h00 * bits2h(W0p[24]) + bits2h(B1p[24]));
                v = __builtin_elementwise_max(v, v * c001h);
                *(uint4*)(awb + 4096 + 2 * 256) = make_uint4(h2bits(v), 0x00003C00u, 0u, 0u);
            }
            *(uint4*)(awb + 4096 + 3 * 256) = make_uint4(0u, 0u, 0u, 0u);  // chunk 7 zeros
        }
        LDS_FENCE();
        floatx4 C[4][2];
        #pragma unroll
        for (int mt = 0; mt < 4; ++mt) {
            const half8 A0 = __builtin_bit_cast(half8, *(const uint4*)(arb + mt * 1024));
            const half8 A1 = __builtin_bit_cast(half8, *(const uint4*)(arb + 4096 + mt * 1024));
            C[mt][0] = __builtin_amdgcn_mfma_f32_16x16x32_f16(A0, __builtin_bit_cast(half8, Bh[0][0]), ZC,       0, 0, 0);
            C[mt][0] = __builtin_amdgcn_mfma_f32_16x16x32_f16(A1, __builtin_bit_cast(half8, Bh[0][1]), C[mt][0], 0, 0, 0);
            C[mt][1] = __builtin_amdgcn_mfma_f32_16x16x32_f16(A0, __builtin_bit_cast(half8, Bh[1][0]), ZC,       0, 0, 0);
            C[mt][1] = __builtin_amdgcn_mfma_f32_16x16x32_f16(A1, __builtin_bit_cast(half8, Bh[1][1]), C[mt][1], 0, 0, 0);
        }
        LDS_FENCE();
        #pragma unroll
        for (int mt = 0; mt < 4; ++mt)
            #pragma unroll
            for (int i = 0; i < 4; ++i)
                *(float*)(cw1 + mt * 1280 + i * 80) = C[mt][1][i];   // garbage lanes wrap
        LDS_FENCE();
        #pragma unroll
        for (int mt = 0; mt < 4; ++mt)
            #pragma unroll
            for (int i = 0; i < 4; ++i)
                *(float*)(cw0 + mt * 1280 + i * 80) = C[mt][0][i];   // real cols 0..15 win
        LDS_FENCE();
        float a2[20];
        #pragma unroll
        for (int p = 0; p < 5; ++p) {
            const float4 v = *(const float4*)(crb + p * 16);
            a2[4 * p] = v.x; a2[4 * p + 1] = v.y; a2[4 * p + 2] = v.z; a2[4 * p + 3] = v.w;
        }
        LDS_FENCE();
        float nh0 = bh3[0], nh1 = bh3[1];
        #pragma unroll
        for (int i = 0; i < 20; ++i) {
            const float a = lrelu(a2[i]);
            nh0 = fmaf(a, Wh3[2 * i], nh0);
            nh1 = fmaf(a, Wh3[2 * i + 1], nh1);
        }
        h0 = lrelu(nh0); h1 = lrelu(nh1);

        // ======== z path (uses NEW h; z weights pre-scaled by -log2e) ========
        #pragma unroll
        for (int c = 0; c < 6; ++c) {
            unsigned int dw[4];
            #pragma unroll
            for (int p = 0; p < 4; ++p) {
                const int k = c * 8 + 2 * p;
                const float y0 = fmaf(h1, Wz1s[50 + k],     fmaf(h0, Wz1s[k],     bz1s[k]));
                const float y1 = fmaf(h1, Wz1s[50 + k + 1], fmaf(h0, Wz1s[k + 1], bz1s[k + 1]));
                dw[p] = pkrtz_u(sigm2(y0), sigm2(y1));
            }
            *(uint4*)(awb + (c >> 2) * 4096 + (c & 3) * 256)
                = make_uint4(dw[0], dw[1], dw[2], dw[3]);
        }
        {
            const float y48 = fmaf(h1, Wz1s[98], fmaf(h0, Wz1s[48], bz1s[48]));
            const float y49 = fmaf(h1, Wz1s[99], fmaf(h0, Wz1s[49], bz1s[49]));
            *(uint4*)(awb + 4096 + 2 * 256)
                = make_uint4(pkrtz_u(sigm2(y48), sigm2(y49)), 0x00003C00u, 0u, 0u);
        }
        *(uint4*)(awb + 4096 + 3 * 256) = make_uint4(0u, 0u, 0u, 0u);
        LDS_FENCE();
        #pragma unroll
        for (int mt = 0; mt < 4; ++mt) {
            const half8 A0 = __builtin_bit_cast(half8, *(const uint4*)(arb + mt * 1024));
            const half8 A1 = __builtin_bit_cast(half8, *(const uint4*)(arb + 4096 + mt * 1024));
            C[mt][0] = __builtin_amdgcn_mfma_f32_16x16x32_f16(A0, __builtin_bit_cast(half8, Bz[0][0]), ZC,       0, 0, 0);
            C[mt][0] = __builtin_amdgcn_mfma_f32_16x16x32_f16(A1, __builtin_bit_cast(half8, Bz[0][1]), C[mt][0], 0, 0, 0);
            C[mt][1] = __builtin_amdgcn_mfma_f32_16x16x32_f16(A0, __builtin_bit_cast(half8, Bz[1][0]), ZC,       0, 0, 0);
            C[mt][1] = __builtin_amdgcn_mfma_f32_16x16x32_f16(A1, __builtin_bit_cast(half8, Bz[1][1]), C[mt][1], 0, 0, 0);
        }
        LDS_FENCE();
        #pragma unroll
        for (int mt = 0; mt < 4; ++mt)
            #pragma unroll
            for (int i = 0; i < 4; ++i)
                *(float*)(cw1 + mt * 1280 + i * 80) = C[mt][1][i];
        LDS_FENCE();
        #pragma unroll
        for (int mt = 0; mt < 4; ++mt)
            #pragma unroll
            for (int i = 0; i < 4; ++i)
                *(float*)(cw0 + mt * 1280 + i * 80) = C[mt][0][i];
        LDS_FENCE();
        #pragma unroll
        for (int p = 0; p < 5; ++p) {
            const float4 v = *(const float4*)(crb + p * 16);
            a2[4 * p] = v.x; a2[4 * p + 1] = v.y; a2[4 * p + 2] = v.z; a2[4 * p + 3] = v.w;
        }
        LDS_FENCE();
        float zo0 = bz3s[0], zo1 = bz3s[1];
        #pragma unroll
        for (int i = 0; i < 20; ++i) {
            const float zz = sigm2(a2[i]);
            zo0 = fmaf(zz, Wz3s[2 * i], zo0);
            zo1 = fmaf(zz, Wz3s[2 * i + 1], zo1);
        }
        if (ok) {
            float2 o; o.x = sigm2(zo0); o.y = sigm2(zo1);
            *(float2*)(orow + 2 * s) = o;
        }
    }
}

extern "C" void kernel_launch(void* const* d_in, const int* in_sizes, int n_in,
                              void* d_out, int out_size, void* d_ws, size_t ws_size,
                              hipStream_t stream) {
    const float* w   = (const float*)d_in[0];
    const float* Wh1 = (const float*)d_in[1];
    const float* bh1 = (const float*)d_in[2];
    const float* Wh2 = (const float*)d_in[3];
    const float* bh2 = (const float*)d_in[4];
    const float* Wh3 = (const float*)d_in[5];
    const float* bh3 = (const float*)d_in[6];
    const float* Wz1 = (const float*)d_in[7];
    const float* bz1 = (const float*)d_in[8];
    const float* Wz2 = (const float*)d_in[9];
    const float* bz2 = (const float*)d_in[10];
    const float* Wz3 = (const float*)d_in[11];
    const float* bz3 = (const float*)d_in[12];
    float* out = (float*)d_out;

    pack_kernel<<<1, 256, 0, stream>>>(Wh1, bh1, Wh2, bh2, Wz1, bz1, Wz2, bz2,
                                       Wz3, bz3, (char*)d_ws);

    const int nrows = in_sizes[0] / 2;  // w is [B,2]
    const int blocks = (nrows + THREADS - 1) / THREADS;
    recurrent_kernel<<<blocks, THREADS, 0, stream>>>(
        w, Wh3, bh3, (const char*)d_ws, out, nrows);
}

// Round 12
// 628.794 us; speedup vs baseline: 2.7945x; 1.0672x over previous
//
#include <hip/hip_runtime.h>
#include <math.h>

#define STEPS 19
#define THREADS 256
#define L2E 1.44269504088896340736f   // log2(e)

typedef _Float16 half8   __attribute__((ext_vector_type(8)));   // MFMA A/B frag
typedef float    floatx4 __attribute__((ext_vector_type(4)));   // MFMA C/D frag
typedef __fp16   half2_t __attribute__((ext_vector_type(2)));   // packed f16 pair

#define WAVE_LDS 8192   // A-frags [kb][mt][fraglane]*16B = 2*4*64*16; C-stage (5120B) overlays

// d_ws byte offsets
#define WS_BH    0      // h-layer2 B-frags  [u][kk][lane]*16B = 4096
#define WS_BZ    4096   // z-layer2 B-frags (pre-scaled by -log2e) = 4096
#define WS_H1W0  8192   // 25 half2: {Wh1[0][2q],Wh1[0][2q+1]}
#define WS_H1W1  8292   // 25 half2: row 1
#define WS_H1B   8392   // 25 half2: bh1 pairs
#define WS_Z1W0  8492   // 25 half2: -L2E*Wz1 row 0 pairs
#define WS_Z1W1  8592   // 25 half2: -L2E*Wz1 row 1 pairs
#define WS_Z1B   8692   // 25 half2: -L2E*bz1 pairs
#define WS_WZ3   8792   // 40  f32: -L2E*Wz3
#define WS_BZ3   8952   // 2   f32: -L2E*bz3

#define LDS_FENCE() asm volatile("" ::: "memory")

__device__ __forceinline__ float lrelu(float x) { return fmaxf(x, 0.01f * x); }
__device__ __forceinline__ float sigm2(float y) {   // sigmoid, -log2e pre-folded
    return __builtin_amdgcn_rcpf(1.0f + __builtin_amdgcn_exp2f(y));
}
__device__ __forceinline__ unsigned int pkrtz_u(float a, float b) {
    return __builtin_bit_cast(unsigned int, __builtin_amdgcn_cvt_pkrtz(a, b));
}
__device__ __forceinline__ unsigned int packh2(float a, float b) {
    half2_t h; h.x = (__fp16)a; h.y = (__fp16)b;
    return __builtin_bit_cast(unsigned int, h);
}
__device__ __forceinline__ unsigned int h2bits(half2_t h) {
    return __builtin_bit_cast(unsigned int, h);
}
__device__ __forceinline__ half2_t bits2h(unsigned int u) {
    return __builtin_bit_cast(half2_t, u);
}

// packed-f16 sigmoid of a pre-scaled pair: y = -log2e*x; out = 1/(1+2^y)
__device__ __forceinline__ half2_t sigm_h2(half2_t y) {
#if __has_builtin(__builtin_elementwise_exp2) && __has_builtin(__builtin_amdgcn_rcph)
    half2_t e = __builtin_elementwise_exp2(y);            // 2x v_exp_f16
    e = e + (half2_t){(__fp16)1.0f, (__fp16)1.0f};        // v_pk_add_f16
    half2_t r;
    r.x = __builtin_amdgcn_rcph(e.x);                     // v_rcp_f16
    r.y = __builtin_amdgcn_rcph(e.y);
    return r;
#else
    return bits2h(pkrtz_u(sigm2((float)y.x), sigm2((float)y.y)));
#endif
}

// --- pack kernel ---
__global__ __launch_bounds__(256) void pack_kernel(
    const float* __restrict__ Wh1, const float* __restrict__ bh1,
    const float* __restrict__ Wh2, const float* __restrict__ bh2,
    const float* __restrict__ Wz1, const float* __restrict__ bz1,
    const float* __restrict__ Wz2, const float* __restrict__ bz2,
    const float* __restrict__ Wz3, const float* __restrict__ bz3,
    char* __restrict__ ws)
{
    const int t = threadIdx.x;
    // B-frags (16x16x32 f16): lane holds B[k=(lane>>4)*8+j][n=lane&15], j=0..7.
    // Bias row at k==50 (A supplies 1.0); k>50 rows ZERO (annihilate A pad).
    for (int e = t; e < 512; e += 256) {
        const int layer = e >> 8, r = e & 255;
        const int u = r >> 7, kk = (r >> 6) & 1, lane = r & 63;
        const int n = u * 16 + (lane & 15);
        const float* W2 = layer ? Wz2 : Wh2;
        const float* b2 = layer ? bz2 : bh2;
        const float scale = layer ? -L2E : 1.0f;
        unsigned int dw[4];
        #pragma unroll
        for (int d = 0; d < 4; ++d) {
            float v[2];
            #pragma unroll
            for (int h = 0; h < 2; ++h) {
                const int k = kk * 32 + ((lane >> 4) & 3) * 8 + 2 * d + h;
                float x = 0.0f;
                if (n < 20) {
                    if (k < 50)       x = W2[k * 20 + n] * scale;
                    else if (k == 50) x = b2[n] * scale;
                }
                v[h] = x;
            }
            dw[d] = packh2(v[0], v[1]);
        }
        *(uint4*)(ws + (layer ? WS_BZ : WS_BH) + (size_t)((u * 2 + kk) * 64 + lane) * 16)
            = make_uint4(dw[0], dw[1], dw[2], dw[3]);
    }
    if (t < 25) {
        ((unsigned int*)(ws + WS_H1W0))[t] = packh2(Wh1[2 * t],      Wh1[2 * t + 1]);
        ((unsigned int*)(ws + WS_H1W1))[t] = packh2(Wh1[50 + 2 * t], Wh1[51 + 2 * t]);
        ((unsigned int*)(ws + WS_H1B))[t]  = packh2(bh1[2 * t],      bh1[2 * t + 1]);
        ((unsigned int*)(ws + WS_Z1W0))[t] = packh2(-L2E * Wz1[2 * t],      -L2E * Wz1[2 * t + 1]);
        ((unsigned int*)(ws + WS_Z1W1))[t] = packh2(-L2E * Wz1[50 + 2 * t], -L2E * Wz1[51 + 2 * t]);
        ((unsigned int*)(ws + WS_Z1B))[t]  = packh2(-L2E * bz1[2 * t],      -L2E * bz1[2 * t + 1]);
    }
    if (t < 40)  ((float*)(ws + WS_WZ3))[t] = -L2E * Wz3[t];
    if (t < 2)   ((float*)(ws + WS_BZ3))[t] = -L2E * bz3[t];
}

__global__ __launch_bounds__(THREADS)
__attribute__((amdgpu_waves_per_eu(2)))   // min 2 => RA <= 256 VGPR; no max cap
void recurrent_kernel(
    const float* __restrict__ w,
    const float* __restrict__ Wh3, const float* __restrict__ bh3,
    const char* __restrict__ ws,
    float* __restrict__ out, int nrows)
{
    __shared__ __align__(16) char lds[4 * WAVE_LDS];
    const int t    = threadIdx.x;
    const int lane = t & 63;
    const int wid  = t >> 6;
    const int lq   = (lane >> 4) & 3;
    const int ll   = lane & 15;
    char* ldsw = lds + wid * WAVE_LDS;

    // A-frag staging bases (conflict-free, analyzed r10).
    char* awb = ldsw + (lane >> 4) * 1024 + (lane & 15) * 16;
    const char* arb = ldsw + lane * 16;
    // C-stage (overlays A region): row stride 20 dwords; u=1 invalid lanes wrap and
    // are overwritten by later u=0 writes (fence-ordered; DS in-order per wave).
    const int cmod = (ll < 4) ? (16 + ll) : (ll - 4);
    char* cw0 = ldsw + lq * 320 + ll * 4;
    char* cw1 = ldsw + lq * 320 + cmod * 4;
    const char* crb = ldsw + lane * 80;

    // B fragments: loaded once, reused all 19 steps.
    uint4 Bh[2][2], Bz[2][2];
    #pragma unroll
    for (int u = 0; u < 2; ++u)
        #pragma unroll
        for (int kk = 0; kk < 2; ++kk) {
            Bh[u][kk] = *(const uint4*)(ws + WS_BH + (size_t)((u * 2 + kk) * 64 + lane) * 16);
            Bz[u][kk] = *(const uint4*)(ws + WS_BZ + (size_t)((u * 2 + kk) * 64 + lane) * 16);
        }
    const unsigned int* W0p  = (const unsigned int*)(ws + WS_H1W0);
    const unsigned int* W1p  = (const unsigned int*)(ws + WS_H1W1);
    const unsigned int* B1p  = (const unsigned int*)(ws + WS_H1B);
    const unsigned int* ZW0p = (const unsigned int*)(ws + WS_Z1W0);
    const unsigned int* ZW1p = (const unsigned int*)(ws + WS_Z1W1);
    const unsigned int* ZB1p = (const unsigned int*)(ws + WS_Z1B);
    const float* Wz3s = (const float*)(ws + WS_WZ3);
    const float* bz3s = (const float*)(ws + WS_BZ3);

    const half2_t c001h = {(__fp16)0.01f, (__fp16)0.01f};
    const floatx4 ZC = {0.0f, 0.0f, 0.0f, 0.0f};   // persistent zero C-operand

    const int row = blockIdx.x * THREADS + t;
    const bool ok = row < nrows;
    const float2 w2 = *(const float2*)(w + 2 * (size_t)(ok ? row : 0));
    float h0 = w2.x, h1 = w2.y;
    float* orow = out + (size_t)row * (STEPS * 2);

    #pragma unroll 1
    for (int s = 0; s < STEPS; ++s) {
        // ======== h path: L1 packed f16, direct frag staging ========
        {
            const __fp16 h0h = (__fp16)h0, h1h = (__fp16)h1;
            const half2_t h00 = {h0h, h0h};
            const half2_t h11 = {h1h, h1h};
            #pragma unroll
            for (int c = 0; c < 6; ++c) {
                unsigned int dw[4];
                #pragma unroll
                for (int p = 0; p < 4; ++p) {
                    const int q = c * 4 + p;         // pair q -> k=2q,2q+1
                    half2_t v = h11 * bits2h(W1p[q]) + (h00 * bits2h(W0p[q]) + bits2h(B1p[q]));
                    v = __builtin_elementwise_max(v, v * c001h);   // packed lrelu
                    dw[p] = h2bits(v);
                }
                *(uint4*)(awb + (c >> 2) * 4096 + (c & 3) * 256)
                    = make_uint4(dw[0], dw[1], dw[2], dw[3]);
            }
            {   // chunk 6: pair24 + bias slot (k=50 -> 1.0) + zeros
                half2_t v = h11 * bits2h(W1p[24]) + (h00 * bits2h(W0p[24]) + bits2h(B1p[24]));
                v = __builtin_elementwise_max(v, v * c001h);
                *(uint4*)(awb + 4096 + 2 * 256) = make_uint4(h2bits(v), 0x00003C00u, 0u, 0u);
            }
            *(uint4*)(awb + 4096 + 3 * 256) = make_uint4(0u, 0u, 0u, 0u);  // chunk 7 zeros
        }
        LDS_FENCE();
        floatx4 C[4][2];
        #pragma unroll
        for (int mt = 0; mt < 4; ++mt) {
            const half8 A0 = __builtin_bit_cast(half8, *(const uint4*)(arb + mt * 1024));
            const half8 A1 = __builtin_bit_cast(half8, *(const uint4*)(arb + 4096 + mt * 1024));
            C[mt][0] = __builtin_amdgcn_mfma_f32_16x16x32_f16(A0, __builtin_bit_cast(half8, Bh[0][0]), ZC,       0, 0, 0);
            C[mt][0] = __builtin_amdgcn_mfma_f32_16x16x32_f16(A1, __builtin_bit_cast(half8, Bh[0][1]), C[mt][0], 0, 0, 0);
            C[mt][1] = __builtin_amdgcn_mfma_f32_16x16x32_f16(A0, __builtin_bit_cast(half8, Bh[1][0]), ZC,       0, 0, 0);
            C[mt][1] = __builtin_amdgcn_mfma_f32_16x16x32_f16(A1, __builtin_bit_cast(half8, Bh[1][1]), C[mt][1], 0, 0, 0);
        }
        LDS_FENCE();
        #pragma unroll
        for (int mt = 0; mt < 4; ++mt)
            #pragma unroll
            for (int i = 0; i < 4; ++i)
                *(float*)(cw1 + mt * 1280 + i * 80) = C[mt][1][i];   // garbage lanes wrap
        LDS_FENCE();
        #pragma unroll
        for (int mt = 0; mt < 4; ++mt)
            #pragma unroll
            for (int i = 0; i < 4; ++i)
                *(float*)(cw0 + mt * 1280 + i * 80) = C[mt][0][i];   // real cols 0..15 win
        LDS_FENCE();
        float a2[20];
        #pragma unroll
        for (int p = 0; p < 5; ++p) {
            const float4 v = *(const float4*)(crb + p * 16);
            a2[4 * p] = v.x; a2[4 * p + 1] = v.y; a2[4 * p + 2] = v.z; a2[4 * p + 3] = v.w;
        }
        LDS_FENCE();
        float nh0 = bh3[0], nh1 = bh3[1];
        #pragma unroll
        for (int i = 0; i < 20; ++i) {
            const float a = lrelu(a2[i]);
            nh0 = fmaf(a, Wh3[2 * i], nh0);
            nh1 = fmaf(a, Wh3[2 * i + 1], nh1);
        }
        h0 = lrelu(nh0); h1 = lrelu(nh1);

        // ======== z path: L1 packed f16 incl. f16 sigmoid (weights -log2e scaled) ====
        {
            const __fp16 g0h = (__fp16)h0, g1h = (__fp16)h1;
            const half2_t g00 = {g0h, g0h};
            const half2_t g11 = {g1h, g1h};
            #pragma unroll
            for (int c = 0; c < 6; ++c) {
                unsigned int dw[4];
                #pragma unroll
                for (int p = 0; p < 4; ++p) {
                    const int q = c * 4 + p;
                    half2_t y = g11 * bits2h(ZW1p[q]) + (g00 * bits2h(ZW0p[q]) + bits2h(ZB1p[q]));
                    dw[p] = h2bits(sigm_h2(y));
                }
                *(uint4*)(awb + (c >> 2) * 4096 + (c & 3) * 256)
                    = make_uint4(dw[0], dw[1], dw[2], dw[3]);
            }
            {
                half2_t y = g11 * bits2h(ZW1p[24]) + (g00 * bits2h(ZW0p[24]) + bits2h(ZB1p[24]));
                *(uint4*)(awb + 4096 + 2 * 256)
                    = make_uint4(h2bits(sigm_h2(y)), 0x00003C00u, 0u, 0u);
            }
            *(uint4*)(awb + 4096 + 3 * 256) = make_uint4(0u, 0u, 0u, 0u);
        }
        LDS_FENCE();
        #pragma unroll
        for (int mt = 0; mt < 4; ++mt) {
            const half8 A0 = __builtin_bit_cast(half8, *(const uint4*)(arb + mt * 1024));
            const half8 A1 = __builtin_bit_cast(half8, *(const uint4*)(arb + 4096 + mt * 1024));
            C[mt][0] = __builtin_amdgcn_mfma_f32_16x16x32_f16(A0, __builtin_bit_cast(half8, Bz[0][0]), ZC,       0, 0, 0);
            C[mt][0] = __builtin_amdgcn_mfma_f32_16x16x32_f16(A1, __builtin_bit_cast(half8, Bz[0][1]), C[mt][0], 0, 0, 0);
            C[mt][1] = __builtin_amdgcn_mfma_f32_16x16x32_f16(A0, __builtin_bit_cast(half8, Bz[1][0]), ZC,       0, 0, 0);
            C[mt][1] = __builtin_amdgcn_mfma_f32_16x16x32_f16(A1, __builtin_bit_cast(half8, Bz[1][1]), C[mt][1], 0, 0, 0);
        }
        LDS_FENCE();
        #pragma unroll
        for (int mt = 0; mt < 4; ++mt)
            #pragma unroll
            for (int i = 0; i < 4; ++i)
                *(float*)(cw1 + mt * 1280 + i * 80) = C[mt][1][i];
        LDS_FENCE();
        #pragma unroll
        for (int mt = 0; mt < 4; ++mt)
            #pragma unroll
            for (int i = 0; i < 4; ++i)
                *(float*)(cw0 + mt * 1280 + i * 80) = C[mt][0][i];
        LDS_FENCE();
        #pragma unroll
        for (int p = 0; p < 5; ++p) {
            const float4 v = *(const float4*)(crb + p * 16);
            a2[4 * p] = v.x; a2[4 * p + 1] = v.y; a2[4 * p + 2] = v.z; a2[4 * p + 3] = v.w;
        }
        LDS_FENCE();
        float zo0 = bz3s[0], zo1 = bz3s[1];
        #pragma unroll
        for (int i = 0; i < 20; ++i) {
            const float zz = sigm2(a2[i]);
            zo0 = fmaf(zz, Wz3s[2 * i], zo0);
            zo1 = fmaf(zz, Wz3s[2 * i + 1], zo1);
        }
        if (ok) {
            float2 o; o.x = sigm2(zo0); o.y = sigm2(zo1);
            *(float2*)(orow + 2 * s) = o;
        }
    }
}

extern "C" void kernel_launch(void* const* d_in, const int* in_sizes, int n_in,
                              void* d_out, int out_size, void* d_ws, size_t ws_size,
                              hipStream_t stream) {
    const float* w   = (const float*)d_in[0];
    const float* Wh1 = (const float*)d_in[1];
    const float* bh1 = (const float*)d_in[2];
    const float* Wh2 = (const float*)d_in[3];
    const float* bh2 = (const float*)d_in[4];
    const float* Wh3 = (const float*)d_in[5];
    const float* bh3 = (const float*)d_in[6];
    const float* Wz1 = (const float*)d_in[7];
    const float* bz1 = (const float*)d_in[8];
    const float* Wz2 = (const float*)d_in[9];
    const float* bz2 = (const float*)d_in[10];
    const float* Wz3 = (const float*)d_in[11];
    const float* bz3 = (const float*)d_in[12];
    float* out = (float*)d_out;

    pack_kernel<<<1, 256, 0, stream>>>(Wh1, bh1, Wh2, bh2, Wz1, bz1, Wz2, bz2,
                                       Wz3, bz3, (char*)d_ws);

    const int nrows = in_sizes[0] / 2;  // w is [B,2]
    const int blocks = (nrows + THREADS - 1) / THREADS;
    recurrent_kernel<<<blocks, THREADS, 0, stream>>>(
        w, Wh3, bh3, (const char*)d_ws, out, nrows);
}